// Round 6
// baseline (137.964 us; speedup 1.0000x reference)
//
#include <hip/hip_runtime.h>

#define NNZ 32
#define HIDDEN 512

__device__ __forceinline__ uint2 cvt4_bf16(uint4 v) {
    #define CV(u) (((u) + 0x7FFFu + (((u) >> 16) & 1u)) >> 16)
    uint2 o;
    o.x = CV(v.x) | (CV(v.y) << 16);
    o.y = CV(v.z) | (CV(v.w) << 16);
    #undef CV
    return o;
}

// ---------------- phase 1: fp32 gather (chunk0) overlapped with table/w1 cvt ----------------
// blocks [0, GB)        : r2-style fp32 block gather, sample = blockIdx.x
// blocks [GB, GB+16)    : d1_w fp32->bf16
// blocks [GB+16, end)   : ft_weight fp32->bf16, grid-stride
__global__ __launch_bounds__(256) void nnue_phase1(
    const int* __restrict__ white_idx, const int* __restrict__ black_idx,
    const int* __restrict__ stm,
    const float* __restrict__ white_vals, const float* __restrict__ black_vals,
    const float* __restrict__ ft_weight,
    const float* __restrict__ d1_w, const float* __restrict__ d1_b,
    const float* __restrict__ d2_w, const float* __restrict__ d2_b,
    const float* __restrict__ out_w, const float* __restrict__ out_b,
    float* __restrict__ out,
    uint2* __restrict__ tblb, uint2* __restrict__ w1b,
    int GB, int nCvtBlocks, int n4, int n4w)
{
    const int bid = blockIdx.x;
    const int tid = threadIdx.x;

    if (bid >= GB) {
        if (bid < GB + 16) {
            const int i = (bid - GB) * 256 + tid;
            if (i < n4w)
                w1b[i] = cvt4_bf16(reinterpret_cast<const uint4*>(d1_w)[i]);
        } else {
            const int stride = nCvtBlocks * 256;
            for (int i = (bid - GB - 16) * 256 + tid; i < n4; i += stride)
                tblb[i] = cvt4_bf16(reinterpret_cast<const uint4*>(ft_weight)[i]);
        }
        return;
    }

    // ---- fp32 block gather (round-2 kernel, known good) ----
    const int b = bid;

    __shared__ int   s_idx[64];
    __shared__ float s_val[64];
    __shared__ float s_accB[HIDDEN];
    __shared__ float xs[HIDDEN];
    __shared__ float part[32][9];
    __shared__ float h1s[32];
    __shared__ float h2s[32];

    if (tid < 64) {
        const int sd = tid >> 5;
        const int n  = tid & 31;
        const int*   ip = sd ? black_idx  : white_idx;
        const float* vp = sd ? black_vals : white_vals;
        int   id = ip[b * NNZ + n];
        float v  = vp[b * NNZ + n];
        if (id < 0) { id = 0; v = 0.f; }
        s_idx[tid] = id;
        s_val[tid] = v;
    }
    __syncthreads();

    const int side = tid >> 7;
    const int lane = tid & 127;
    const int base = side << 5;

    const float4* W = reinterpret_cast<const float4*>(ft_weight);
    float4 acc = make_float4(0.f, 0.f, 0.f, 0.f);
    #pragma unroll
    for (int c = 0; c < NNZ; c += 8) {
        float4 w[8];
        float  vv[8];
        #pragma unroll
        for (int u = 0; u < 8; ++u) {
            const int n = base + c + u;
            w[u]  = W[(size_t)s_idx[n] * (HIDDEN / 4) + lane];
            vv[u] = s_val[n];
        }
        #pragma unroll
        for (int u = 0; u < 8; ++u) {
            acc.x = fmaf(vv[u], w[u].x, acc.x);
            acc.y = fmaf(vv[u], w[u].y, acc.y);
            acc.z = fmaf(vv[u], w[u].z, acc.z);
            acc.w = fmaf(vv[u], w[u].w, acc.w);
        }
    }

    if (side == 1) reinterpret_cast<float4*>(s_accB)[lane] = acc;
    __syncthreads();
    if (side == 0) {
        const float4 aB  = reinterpret_cast<const float4*>(s_accB)[lane];
        const float sgn  = (stm[b] == 0) ? 1.f : -1.f;
        const float inv64 = 1.0f / 64.0f;
        float4 x;
        x.x = fmaxf(sgn * (acc.x - aB.x) * inv64, 0.f);
        x.y = fmaxf(sgn * (acc.y - aB.y) * inv64, 0.f);
        x.z = fmaxf(sgn * (acc.z - aB.z) * inv64, 0.f);
        x.w = fmaxf(sgn * (acc.w - aB.w) * inv64, 0.f);
        reinterpret_cast<float4*>(xs)[lane] = x;
    }
    __syncthreads();
    {
        const int o = tid & 31;
        const int j = tid >> 5;
        const float* w1p = d1_w + o * HIDDEN + j * 64;
        const float* xp  = xs + j * 64;
        float p = 0.f;
        #pragma unroll
        for (int k = 0; k < 64; ++k) p = fmaf(xp[k], w1p[k], p);
        part[o][j] = p;
    }
    __syncthreads();
    if (tid < 32) {
        const float inv64 = 1.0f / 64.0f;
        float s = d1_b[tid];
        #pragma unroll
        for (int j = 0; j < 8; ++j) s += part[tid][j];
        h1s[tid] = fmaxf(s * inv64, 0.f);
    }
    __syncthreads();
    if (tid < 32) {
        const float inv64 = 1.0f / 64.0f;
        const float* w2p = d2_w + tid * 32;
        float s = d2_b[tid];
        #pragma unroll
        for (int k = 0; k < 32; ++k) s = fmaf(h1s[k], w2p[k], s);
        h2s[tid] = fmaxf(s * inv64, 0.f);
    }
    __syncthreads();
    if (tid == 0) {
        float s = out_b[0];
        #pragma unroll
        for (int k = 0; k < 32; ++k) s = fmaf(h2s[k], out_w[k], s);
        out[b] = s * (1.0f / 16.0f);
    }
}

// ---------------- phase 2: wave-per-sample bf16 gather (round-5 kernel, samples [C,B)) ----------------
__global__ __launch_bounds__(256, 5) void nnue_wave(
    const int* __restrict__ white_idx, const int* __restrict__ black_idx,
    const int* __restrict__ stm,
    const float* __restrict__ white_vals, const float* __restrict__ black_vals,
    const uint4* __restrict__ Wq,      // bf16 table, row = 64 uint4 (1 KB)
    const uint2* __restrict__ W1b,     // bf16 d1_w, [32][128] uint2
    const float* __restrict__ d1_b,
    const float* __restrict__ d2_w, const float* __restrict__ d2_b,
    const float* __restrict__ out_w, const float* __restrict__ out_b,
    float* __restrict__ out, int sample0, int B)
{
    const int lane = threadIdx.x & 63;
    const int wv   = threadIdx.x >> 6;
    const int b    = sample0 + ((blockIdx.x << 2) | wv);
    if (b >= B) return;

    __shared__ float xbuf[4][HIDDEN];
    __shared__ float h1buf[4][32];

    int   id;
    float val;
    {
        const int  n = lane & 31;
        const bool w = lane < 32;
        const int*   ip = w ? white_idx  : black_idx;
        const float* vp = w ? white_vals : black_vals;
        id  = ip[b * NNZ + n];
        val = vp[b * NNZ + n];
        if (id < 0) { id = 0; val = 0.f; }
    }

    float accW[8], accB[8];
    #pragma unroll
    for (int j = 0; j < 8; ++j) { accW[j] = 0.f; accB[j] = 0.f; }

    #define FT_BATCH(RB, ACC)                                                         \
    {                                                                                 \
        uint4 w[8]; float vv[8];                                                      \
        _Pragma("unroll")                                                             \
        for (int u = 0; u < 8; ++u) {                                                 \
            const int sid = __builtin_amdgcn_readlane(id, (RB) + u);                  \
            vv[u] = __uint_as_float(                                                  \
                (unsigned)__builtin_amdgcn_readlane(__float_as_int(val), (RB) + u));  \
            w[u] = Wq[(size_t)sid * 64 + lane];                                       \
        }                                                                             \
        _Pragma("unroll")                                                             \
        for (int u = 0; u < 8; ++u) {                                                 \
            const unsigned* pw = (const unsigned*)&w[u];                              \
            _Pragma("unroll")                                                         \
            for (int j = 0; j < 4; ++j) {                                             \
                ACC[2*j]   = fmaf(vv[u], __uint_as_float(pw[j] << 16),         ACC[2*j]);   \
                ACC[2*j+1] = fmaf(vv[u], __uint_as_float(pw[j] & 0xFFFF0000u), ACC[2*j+1]); \
            }                                                                         \
        }                                                                             \
    }

    FT_BATCH(0,  accW) FT_BATCH(8,  accW) FT_BATCH(16, accW) FT_BATCH(24, accW)
    FT_BATCH(32, accB) FT_BATCH(40, accB) FT_BATCH(48, accB) FT_BATCH(56, accB)
    #undef FT_BATCH

    const float sgn   = (stm[b] == 0) ? 1.f : -1.f;
    const float inv64 = 0.015625f;
    float4 x0, x1;
    x0.x = fmaxf(sgn * (accW[0] - accB[0]) * inv64, 0.f);
    x0.y = fmaxf(sgn * (accW[1] - accB[1]) * inv64, 0.f);
    x0.z = fmaxf(sgn * (accW[2] - accB[2]) * inv64, 0.f);
    x0.w = fmaxf(sgn * (accW[3] - accB[3]) * inv64, 0.f);
    x1.x = fmaxf(sgn * (accW[4] - accB[4]) * inv64, 0.f);
    x1.y = fmaxf(sgn * (accW[5] - accB[5]) * inv64, 0.f);
    x1.z = fmaxf(sgn * (accW[6] - accB[6]) * inv64, 0.f);
    x1.w = fmaxf(sgn * (accW[7] - accB[7]) * inv64, 0.f);
    *(float4*)&xbuf[wv][lane * 8]     = x0;
    *(float4*)&xbuf[wv][lane * 8 + 4] = x1;

    const int o = lane >> 1, h = lane & 1;
    const uint2* w1p = W1b + o * 128 + h * 64;
    const float* xh  = &xbuf[wv][h * 256];
    float p = 0.f;
    #pragma unroll 8
    for (int kk = 0; kk < 64; ++kk) {
        const uint2  ww = w1p[kk];
        const float4 xv = *(const float4*)&xh[kk * 4];
        p = fmaf(xv.x, __uint_as_float(ww.x << 16),         p);
        p = fmaf(xv.y, __uint_as_float(ww.x & 0xFFFF0000u), p);
        p = fmaf(xv.z, __uint_as_float(ww.y << 16),         p);
        p = fmaf(xv.w, __uint_as_float(ww.y & 0xFFFF0000u), p);
    }
    p += __shfl_xor(p, 1);
    if (h == 0) h1buf[wv][o] = fmaxf((p + d1_b[o]) * inv64, 0.f);

    const int o2 = lane & 31;
    const float* w2p = d2_w + o2 * 32;
    float q = d2_b[o2];
    #pragma unroll
    for (int k = 0; k < 32; ++k) q = fmaf(h1buf[wv][k], w2p[k], q);
    const float h2 = fmaxf(q * inv64, 0.f);

    float t = h2 * out_w[o2];
    #pragma unroll
    for (int s = 1; s < 32; s <<= 1) t += __shfl_xor(t, s);
    if (lane == 0) out[b] = (t + out_b[0]) * 0.0625f;
}

extern "C" void kernel_launch(void* const* d_in, const int* in_sizes, int n_in,
                              void* d_out, int out_size, void* d_ws, size_t ws_size,
                              hipStream_t stream) {
    const int*   white_idx  = (const int*)d_in[0];
    const int*   black_idx  = (const int*)d_in[1];
    const int*   stm        = (const int*)d_in[2];
    const float* white_vals = (const float*)d_in[3];
    const float* black_vals = (const float*)d_in[4];
    const float* ft_weight  = (const float*)d_in[5];
    const float* d1_w       = (const float*)d_in[7];
    const float* d1_b       = (const float*)d_in[8];
    const float* d2_w       = (const float*)d_in[9];
    const float* d2_b       = (const float*)d_in[10];
    const float* out_w      = (const float*)d_in[11];
    const float* out_b      = (const float*)d_in[12];
    float*       out        = (float*)d_out;

    const int B  = in_sizes[2];            // stm is [B]
    const long long FH  = in_sizes[5];     // F * 512 elements
    const long long W1N = in_sizes[7];     // 32 * 512 elements

    uint2* tblb = (uint2*)d_ws;
    uint2* w1b  = (uint2*)((char*)d_ws + (size_t)FH * 2);

    const int n4  = (int)(FH / 4);
    const int n4w = (int)(W1N / 4);

    // chunk0: samples done at fp32 in phase 1, overlapped with the cvt stream
    int C = 1280;
    if (C > B) C = B & ~3;
    const int nCvtBlocks = 1024;

    // phase 1: fp32 gather for [0,C) + table/w1 conversion
    nnue_phase1<<<C + 16 + nCvtBlocks, 256, 0, stream>>>(
        white_idx, black_idx, stm, white_vals, black_vals,
        ft_weight, d1_w, d1_b, d2_w, d2_b, out_w, out_b, out,
        tblb, w1b, C, nCvtBlocks, n4, n4w);

    // phase 2: bf16 wave gather for [C,B)
    const int rem = B - C;
    if (rem > 0) {
        nnue_wave<<<(rem + 3) / 4, 256, 0, stream>>>(
            white_idx, black_idx, stm, white_vals, black_vals,
            (const uint4*)tblb, (const uint2*)w1b,
            d1_b, d2_w, d2_b, out_w, out_b, out, C, B);
    }
}

// Round 7
// 120.604 us; speedup vs baseline: 1.1439x; 1.1439x over previous
//
#include <hip/hip_runtime.h>

#define NNZ 32
#define HIDDEN 512

__device__ __forceinline__ uint2 cvt4_bf16(uint4 v) {
    #define CV(u) (((u) + 0x7FFFu + (((u) >> 16) & 1u)) >> 16)
    uint2 o;
    o.x = CV(v.x) | (CV(v.y) << 16);
    o.y = CV(v.z) | (CV(v.w) << 16);
    #undef CV
    return o;
}

// ---------------- fused fp32->bf16 conversion: ft_weight (blocks [0,nTb)) + d1_w (16 blocks) ----------------
__global__ __launch_bounds__(256) void cvt_all(const uint4* __restrict__ tbl_in,
                                               uint2* __restrict__ tbl_out, int n4,
                                               const uint4* __restrict__ w1_in,
                                               uint2* __restrict__ w1_out, int n4w,
                                               int nTb)
{
    const int bid = blockIdx.x;
    if (bid < nTb) {
        const int i = bid * 256 + (int)threadIdx.x;
        if (i < n4) tbl_out[i] = cvt4_bf16(tbl_in[i]);
    } else {
        const int i = (bid - nTb) * 256 + (int)threadIdx.x;
        if (i < n4w) w1_out[i] = cvt4_bf16(w1_in[i]);
    }
}

// ---------------- fused NNUE forward: one wave per sample, zero barriers ----------------
__global__ __launch_bounds__(256, 5) void nnue_wave(
    const int* __restrict__ white_idx, const int* __restrict__ black_idx,
    const int* __restrict__ stm,
    const float* __restrict__ white_vals, const float* __restrict__ black_vals,
    const uint4* __restrict__ Wq,      // bf16 table, row = 64 uint4 (1 KB)
    const uint2* __restrict__ W1b,     // bf16 d1_w, [32][128] uint2 (packed k-pairs)
    const float* __restrict__ d1_b,
    const float* __restrict__ d2_w, const float* __restrict__ d2_b,
    const float* __restrict__ out_w, const float* __restrict__ out_b,
    float* __restrict__ out, int B)
{
    const int lane = threadIdx.x & 63;
    const int wv   = threadIdx.x >> 6;
    const int b    = (blockIdx.x << 2) | wv;
    if (b >= B) return;

    __shared__ float xbuf[4][HIDDEN];   // per-wave x slab (wave-synchronous, no barriers)
    __shared__ float h1buf[4][32];

    // ---- stage (idx,val): lane i owns draw i (white i<32, black i>=32) ----
    int   id;
    float val;
    {
        const int  n = lane & 31;
        const bool w = lane < 32;
        const int*   ip = w ? white_idx  : black_idx;
        const float* vp = w ? white_vals : black_vals;
        id  = ip[b * NNZ + n];
        val = vp[b * NNZ + n];
        if (id < 0) { id = 0; val = 0.f; }
    }

    // ---- feature transform: one wave-wide dwordx4 load per row; lane owns dims [8*lane, 8*lane+8) ----
    float accW[8], accB[8];
    #pragma unroll
    for (int j = 0; j < 8; ++j) { accW[j] = 0.f; accB[j] = 0.f; }

    #define FT_BATCH(RB, ACC)                                                         \
    {                                                                                 \
        uint4 w[8]; float vv[8];                                                      \
        _Pragma("unroll")                                                             \
        for (int u = 0; u < 8; ++u) {                                                 \
            const int sid = __builtin_amdgcn_readlane(id, (RB) + u);                  \
            vv[u] = __uint_as_float(                                                  \
                (unsigned)__builtin_amdgcn_readlane(__float_as_int(val), (RB) + u));  \
            w[u] = Wq[(size_t)sid * 64 + lane];                                       \
        }                                                                             \
        _Pragma("unroll")                                                             \
        for (int u = 0; u < 8; ++u) {                                                 \
            const unsigned* pw = (const unsigned*)&w[u];                              \
            _Pragma("unroll")                                                         \
            for (int j = 0; j < 4; ++j) {                                             \
                ACC[2*j]   = fmaf(vv[u], __uint_as_float(pw[j] << 16),         ACC[2*j]);   \
                ACC[2*j+1] = fmaf(vv[u], __uint_as_float(pw[j] & 0xFFFF0000u), ACC[2*j+1]); \
            }                                                                         \
        }                                                                             \
    }

    FT_BATCH(0,  accW) FT_BATCH(8,  accW) FT_BATCH(16, accW) FT_BATCH(24, accW)
    FT_BATCH(32, accB) FT_BATCH(40, accB) FT_BATCH(48, accB) FT_BATCH(56, accB)
    #undef FT_BATCH

    // ---- us/them + relu + scale; publish x to this wave's LDS slab ----
    const float sgn   = (stm[b] == 0) ? 1.f : -1.f;
    const float inv64 = 0.015625f;
    float4 x0, x1;
    x0.x = fmaxf(sgn * (accW[0] - accB[0]) * inv64, 0.f);
    x0.y = fmaxf(sgn * (accW[1] - accB[1]) * inv64, 0.f);
    x0.z = fmaxf(sgn * (accW[2] - accB[2]) * inv64, 0.f);
    x0.w = fmaxf(sgn * (accW[3] - accB[3]) * inv64, 0.f);
    x1.x = fmaxf(sgn * (accW[4] - accB[4]) * inv64, 0.f);
    x1.y = fmaxf(sgn * (accW[5] - accB[5]) * inv64, 0.f);
    x1.z = fmaxf(sgn * (accW[6] - accB[6]) * inv64, 0.f);
    x1.w = fmaxf(sgn * (accW[7] - accB[7]) * inv64, 0.f);
    *(float4*)&xbuf[wv][lane * 8]     = x0;
    *(float4*)&xbuf[wv][lane * 8 + 4] = x1;
    // wave-synchronous: same-wave DS ops are ordered; no barrier needed

    // ---- layer 1: lane = (o, h); half-dot over 256, combine via shfl_xor(1) ----
    const int o = lane >> 1, h = lane & 1;
    const uint2* w1p = W1b + o * 128 + h * 64;
    const float* xh  = &xbuf[wv][h * 256];
    float p = 0.f;
    #pragma unroll 8
    for (int kk = 0; kk < 64; ++kk) {
        const uint2  ww = w1p[kk];
        const float4 xv = *(const float4*)&xh[kk * 4];
        p = fmaf(xv.x, __uint_as_float(ww.x << 16),         p);
        p = fmaf(xv.y, __uint_as_float(ww.x & 0xFFFF0000u), p);
        p = fmaf(xv.z, __uint_as_float(ww.y << 16),         p);
        p = fmaf(xv.w, __uint_as_float(ww.y & 0xFFFF0000u), p);
    }
    p += __shfl_xor(p, 1);
    if (h == 0) h1buf[wv][o] = fmaxf((p + d1_b[o]) * inv64, 0.f);

    // ---- layer 2: all lanes (upper half duplicates), broadcast LDS reads ----
    const int o2 = lane & 31;
    const float* w2p = d2_w + o2 * 32;
    float q = d2_b[o2];
    #pragma unroll
    for (int k = 0; k < 32; ++k) q = fmaf(h1buf[wv][k], w2p[k], q);
    const float h2 = fmaxf(q * inv64, 0.f);

    // ---- head: 32-lane shuffle reduce ----
    float t = h2 * out_w[o2];
    #pragma unroll
    for (int s = 1; s < 32; s <<= 1) t += __shfl_xor(t, s);
    if (lane == 0) out[b] = (t + out_b[0]) * 0.0625f;
}

// ---------------- fp32 block fallback if d_ws too small ----------------
__global__ __launch_bounds__(256) void nnue_fused_f32(
    const int* __restrict__ white_idx, const int* __restrict__ black_idx,
    const int* __restrict__ stm,
    const float* __restrict__ white_vals, const float* __restrict__ black_vals,
    const float* __restrict__ ft_weight,
    const float* __restrict__ d1_w, const float* __restrict__ d1_b,
    const float* __restrict__ d2_w, const float* __restrict__ d2_b,
    const float* __restrict__ out_w, const float* __restrict__ out_b,
    float* __restrict__ out)
{
    const int b   = blockIdx.x;
    const int tid = threadIdx.x;

    __shared__ int   s_idx[64];
    __shared__ float s_val[64];
    __shared__ float s_accB[HIDDEN];
    __shared__ float xs[HIDDEN];
    __shared__ float part[32][9];
    __shared__ float h1s[32];
    __shared__ float h2s[32];

    if (tid < 64) {
        const int sd = tid >> 5;
        const int n  = tid & 31;
        const int*   ip = sd ? black_idx  : white_idx;
        const float* vp = sd ? black_vals : white_vals;
        int   id = ip[b * NNZ + n];
        float v  = vp[b * NNZ + n];
        if (id < 0) { id = 0; v = 0.f; }
        s_idx[tid] = id;
        s_val[tid] = v;
    }
    __syncthreads();

    const int side = tid >> 7;
    const int lane = tid & 127;
    const int base = side << 5;

    const float4* W = reinterpret_cast<const float4*>(ft_weight);
    float4 acc = make_float4(0.f, 0.f, 0.f, 0.f);
    #pragma unroll
    for (int c = 0; c < NNZ; c += 8) {
        float4 w[8];
        float  vv[8];
        #pragma unroll
        for (int u = 0; u < 8; ++u) {
            const int n = base + c + u;
            w[u]  = W[(size_t)s_idx[n] * (HIDDEN / 4) + lane];
            vv[u] = s_val[n];
        }
        #pragma unroll
        for (int u = 0; u < 8; ++u) {
            acc.x = fmaf(vv[u], w[u].x, acc.x);
            acc.y = fmaf(vv[u], w[u].y, acc.y);
            acc.z = fmaf(vv[u], w[u].z, acc.z);
            acc.w = fmaf(vv[u], w[u].w, acc.w);
        }
    }

    if (side == 1) reinterpret_cast<float4*>(s_accB)[lane] = acc;
    __syncthreads();
    if (side == 0) {
        const float4 aB  = reinterpret_cast<const float4*>(s_accB)[lane];
        const float sgn  = (stm[b] == 0) ? 1.f : -1.f;
        const float inv64 = 1.0f / 64.0f;
        float4 x;
        x.x = fmaxf(sgn * (acc.x - aB.x) * inv64, 0.f);
        x.y = fmaxf(sgn * (acc.y - aB.y) * inv64, 0.f);
        x.z = fmaxf(sgn * (acc.z - aB.z) * inv64, 0.f);
        x.w = fmaxf(sgn * (acc.w - aB.w) * inv64, 0.f);
        reinterpret_cast<float4*>(xs)[lane] = x;
    }
    __syncthreads();
    {
        const int o = tid & 31;
        const int j = tid >> 5;
        const float* w1p = d1_w + o * HIDDEN + j * 64;
        const float* xp  = xs + j * 64;
        float p = 0.f;
        #pragma unroll
        for (int k = 0; k < 64; ++k) p = fmaf(xp[k], w1p[k], p);
        part[o][j] = p;
    }
    __syncthreads();
    if (tid < 32) {
        const float inv64 = 1.0f / 64.0f;
        float s = d1_b[tid];
        #pragma unroll
        for (int j = 0; j < 8; ++j) s += part[tid][j];
        h1s[tid] = fmaxf(s * inv64, 0.f);
    }
    __syncthreads();
    if (tid < 32) {
        const float inv64 = 1.0f / 64.0f;
        const float* w2p = d2_w + tid * 32;
        float s = d2_b[tid];
        #pragma unroll
        for (int k = 0; k < 32; ++k) s = fmaf(h1s[k], w2p[k], s);
        h2s[tid] = fmaxf(s * inv64, 0.f);
    }
    __syncthreads();
    if (tid == 0) {
        float s = out_b[0];
        #pragma unroll
        for (int k = 0; k < 32; ++k) s = fmaf(h2s[k], out_w[k], s);
        out[b] = s * (1.0f / 16.0f);
    }
}

extern "C" void kernel_launch(void* const* d_in, const int* in_sizes, int n_in,
                              void* d_out, int out_size, void* d_ws, size_t ws_size,
                              hipStream_t stream) {
    const int*   white_idx  = (const int*)d_in[0];
    const int*   black_idx  = (const int*)d_in[1];
    const int*   stm        = (const int*)d_in[2];
    const float* white_vals = (const float*)d_in[3];
    const float* black_vals = (const float*)d_in[4];
    const float* ft_weight  = (const float*)d_in[5];
    const float* d1_w       = (const float*)d_in[7];
    const float* d1_b       = (const float*)d_in[8];
    const float* d2_w       = (const float*)d_in[9];
    const float* d2_b       = (const float*)d_in[10];
    const float* out_w      = (const float*)d_in[11];
    const float* out_b      = (const float*)d_in[12];
    float*       out        = (float*)d_out;

    const int B  = in_sizes[2];            // stm is [B]
    const long long FH  = in_sizes[5];     // F * 512 elements
    const long long W1N = in_sizes[7];     // 32 * 512 elements

    if (ws_size >= (size_t)(FH * 2 + W1N * 2 + 256)) {
        const int n4  = (int)(FH / 4);
        const int n4w = (int)(W1N / 4);
        uint2* tblb = (uint2*)d_ws;
        uint2* w1b  = (uint2*)((char*)d_ws + (size_t)FH * 2);
        const int nTb = (n4 + 255) / 256;
        const int nWb = (n4w + 255) / 256;
        cvt_all<<<nTb + nWb, 256, 0, stream>>>((const uint4*)ft_weight, tblb, n4,
                                               (const uint4*)d1_w, w1b, n4w, nTb);
        nnue_wave<<<(B + 3) / 4, 256, 0, stream>>>(white_idx, black_idx, stm,
                                                   white_vals, black_vals,
                                                   (const uint4*)tblb, (const uint2*)w1b,
                                                   d1_b, d2_w, d2_b,
                                                   out_w, out_b, out, B);
    } else {
        nnue_fused_f32<<<B, 256, 0, stream>>>(white_idx, black_idx, stm,
                                              white_vals, black_vals,
                                              ft_weight,
                                              d1_w, d1_b, d2_w, d2_b,
                                              out_w, out_b, out);
    }
}